// Round 14
// baseline (60.011 us; speedup 1.0000x reference)
//
#include <hip/hip_runtime.h>
#include <hip/hip_bf16.h>
#include <string.h>

// N=32, C=96, H=W=56. HW=3136, NP=100352.
// d_out = [ out (9,633,792 f32) | fmap (9,633,792 f32) ]
//
// ws layout (float index):
//   [   0, 4608) W1 bf16 A-frags: slot ((g*3+m)*3+k)*64+lane (16 B each),
//                w'[o=16m+(lane&15)][ci=32k+(lane>>4)*8+j], w' = w1*s1
//   [4608, 4800) c1[192] f32: c = b1/s1 (act' = max(x + c, 0))
//   [4800, 6336) W2 bf16 A-frags: slot ((G*2+m))*64+lane,
//                w2[o=G*32+16m+(lane&15)][ci=(lane>>4)*8+j]  (no fold)
//   [6336, 7104) p2[96][8]: c2=b2/s2, w00*s2, w01*s2, w10*s2, w11*s2,
//                ayax packed, off = ay*56+ax, pad
#define WSC_OFF 4608
#define WS_W2F  4800
#define WS_P    6336

#define HW 3136
#define CC 96
#define NB 32

typedef __attribute__((ext_vector_type(8))) short short8;
typedef __attribute__((ext_vector_type(4))) float float4_;

__global__ __launch_bounds__(128) void precompute_k(
    const float* __restrict__ g1, const float* __restrict__ be1,
    const float* __restrict__ m1, const float* __restrict__ v1,
    const float* __restrict__ g2, const float* __restrict__ be2,
    const float* __restrict__ m2, const float* __restrict__ v2,
    const float* __restrict__ w1, const float* __restrict__ w2,
    const float* __restrict__ shift, float* __restrict__ ws) {
  const int t = blockIdx.x * 128 + threadIdx.x;  // 12*128 = 1536 threads
  if (t < 192) {
    float s = g1[t] / sqrtf(v1[t] + 1e-5f);
    float b = be1[t] - m1[t] * s;
    ws[WSC_OFF + t] = b / s;     // gamma > 0 guaranteed
  }
  if (t >= 192 && t < 288) {     // conv2 per-channel params (s2 folded into w)
    int c = t - 192;
    float s = g2[c] / sqrtf(v2[c] + 1e-5f);
    float b = be2[c] - m2[c] * s;
    float dy = shift[2 * c], dx = shift[2 * c + 1];
    float fy = floorf(dy), fx = floorf(dx);
    float wy = dy - fy, wx = dx - fx;
    int ay = (int)fy, ax = (int)fx;
    float* pp = ws + WS_P + c * 8;
    pp[0] = b / s;                       // c2: q = s*relu(f + c2)
    pp[1] = (1.f - wy) * (1.f - wx) * s;
    pp[2] = (1.f - wy) * wx * s;
    pp[3] = wy * (1.f - wx) * s;
    pp[4] = wy * wx * s;
    pp[5] = __int_as_float((ay << 16) | (ax & 0xffff));
    pp[6] = __int_as_float(ay * 56 + ax);
    pp[7] = 0.f;
  }
  if (t < 1152) {                // W1 fragments (scale-folded bf16)
    const int lane = t & 63;
    const int gmk = t >> 6;      // 0..17
    const int k = gmk % 3;
    const int gm = gmk / 3;
    const int m = gm % 3;
    const int g = gm / 3;
    const int o = 16 * m + (lane & 15);
    const int ci0 = 32 * k + (lane >> 4) * 8;
    unsigned int pk[4];
    for (int jj = 0; jj < 4; ++jj) {
      unsigned short us[2];
      for (int h = 0; h < 2; ++h) {
        int ci = ci0 + 2 * jj + h;
        float s = g1[g * 96 + ci] / sqrtf(v1[g * 96 + ci] + 1e-5f);
        float w = w1[(g * 48 + o) * 96 + ci] * s;
        __hip_bfloat16 hb = __float2bfloat16(w);
        memcpy(&us[h], &hb, 2);
      }
      pk[jj] = (unsigned int)us[0] | ((unsigned int)us[1] << 16);
    }
    uint4 val;
    val.x = pk[0]; val.y = pk[1]; val.z = pk[2]; val.w = pk[3];
    ((uint4*)ws)[t] = val;
  } else if (t < 1536) {         // W2 fragments (plain bf16)
    const int s2i = t - 1152;    // 0..383
    const int lane = s2i & 63;
    const int gm = s2i >> 6;     // 0..5
    const int m = gm & 1;
    const int G = gm >> 1;
    const int o = G * 32 + m * 16 + (lane & 15);
    const int k0 = (lane >> 4) * 8;
    unsigned int pk[4];
    for (int jj = 0; jj < 4; ++jj) {
      unsigned short us[2];
      for (int h = 0; h < 2; ++h) {
        __hip_bfloat16 hb = __float2bfloat16(w2[o * 32 + k0 + 2 * jj + h]);
        memcpy(&us[h], &hb, 2);
      }
      pk[jj] = (unsigned int)us[0] | ((unsigned int)us[1] << 16);
    }
    uint4 val;
    val.x = pk[0]; val.y = pk[1]; val.z = pk[2]; val.w = pk[3];
    ((uint4*)(ws + WS_W2F))[s2i] = val;
  }
}

// ---------------------------------------------------------------------------
// K1 (MFMA): fmap = conv1x1_g2( bnrelu1( concat ), w1 )   [r8's exact kernel]
// grid (392, 2) XCD-chunk swizzled (49 strips/XCD, matches K2), block 256.
// Wave: 4 tiles of 16 px, depth-1 register double-buffer prefetch.
// nt-load ONLY on the k==2 (pure prev, read-once) octets: keeps the dead
// prev stream from evicting x/fmap in L2/L3. (nt on K2's loads/stores was
// the r8 regression; nt here measured K1 ~29 us.)
// ---------------------------------------------------------------------------
__global__ __launch_bounds__(256) void k1_conv1(
    const float* __restrict__ x, const float* __restrict__ prev,
    const float* __restrict__ ws, float* __restrict__ fmap) {
  const int tid = threadIdx.x;
  const int lane = tid & 63;
  const int wv = tid >> 6;
  const int g = blockIdx.y;
  const int strip = (blockIdx.x & 7) * 49 + (blockIdx.x >> 3);  // 392 = 8*49
  const int q = lane >> 4;       // 0..3
  const int colL = lane & 15;

  short8 A[3][3];
  const short8* wf = (const short8*)ws;
#pragma unroll
  for (int m = 0; m < 3; ++m)
#pragma unroll
    for (int k = 0; k < 3; ++k)
      A[m][k] = wf[((g * 3 + m) * 3 + k) * 64 + lane];

  float c_[3][8];
#pragma unroll
  for (int k = 0; k < 3; ++k) {
    const float* cp = ws + WSC_OFF + g * 96 + 32 * k + 8 * q;
#pragma unroll
    for (int j = 0; j < 8; ++j) c_[k][j] = cp[j];
  }

  const int P0 = strip * 256 + wv * 64;   // 64 | 3136: n const per wave
  const int n = P0 / HW;
  const int pw = P0 - n * HW;
  const size_t nb = (size_t)n * CC * HW;

  // per-k source base (k=0: all x; k=1: mixed x/prev by q; k=2: all prev)
  const float* sb[3];
#pragma unroll
  for (int k = 0; k < 3; ++k) {
    const int ci0 = 32 * k + 8 * q;
    sb[k] = (ci0 < 48)
        ? (x + nb + (size_t)(g * 48 + ci0) * HW)
        : (prev + nb + (size_t)((1 - g) * 48 + (ci0 - 48)) * HW);
  }
  float* fb = fmap + nb + (size_t)(g * 48) * HW;

  float ab[2][3][8];
  {
    const int c0 = pw + colL;
#pragma unroll
    for (int k = 0; k < 3; ++k)
#pragma unroll
      for (int j = 0; j < 8; ++j)
        ab[0][k][j] = (k == 2)
            ? __builtin_nontemporal_load(sb[k] + (size_t)j * HW + c0)
            : sb[k][(size_t)j * HW + c0];
  }

#pragma unroll
  for (int t = 0; t < 4; ++t) {
    const int cur = t & 1;
    if (t < 3) {                 // prefetch next tile while computing this one
      const int cn = pw + (t + 1) * 16 + colL;
#pragma unroll
      for (int k = 0; k < 3; ++k)
#pragma unroll
        for (int j = 0; j < 8; ++j)
          ab[cur ^ 1][k][j] = (k == 2)
              ? __builtin_nontemporal_load(sb[k] + (size_t)j * HW + cn)
              : sb[k][(size_t)j * HW + cn];
    }

    const int col = pw + t * 16 + colL;
    float4_ D[3] = {{0.f, 0.f, 0.f, 0.f}, {0.f, 0.f, 0.f, 0.f},
                    {0.f, 0.f, 0.f, 0.f}};
#pragma unroll
    for (int k = 0; k < 3; ++k) {
      short8 B;
#pragma unroll
      for (int j = 0; j < 8; ++j) {
        float f = fmaxf(ab[cur][k][j] + c_[k][j], 0.f);
        __hip_bfloat16 hb = __float2bfloat16(f);
        unsigned short us;
        memcpy(&us, &hb, 2);
        B[j] = (short)us;
      }
#pragma unroll
      for (int m = 0; m < 3; ++m)
        D[m] = __builtin_amdgcn_mfma_f32_16x16x32_bf16(A[m][k], B, D[m],
                                                       0, 0, 0);
    }

#pragma unroll
    for (int m = 0; m < 3; ++m)
#pragma unroll
      for (int r = 0; r < 4; ++r)
        fb[(size_t)(16 * m + q * 4 + r) * HW + col] = D[m][r];
  }
}

// ---------------------------------------------------------------------------
// K2 (MFMA): out = conv1x1_g3( active_shift( bnrelu2(fmap) ), w2 ) + x
// [r11's exact kernel — measured ~14 us]
// grid (392, 3) swizzled; block 512 = 8 waves; wave = 2 tiles of 16 px.
// s2 folded into tap weights. Plain loads/stores (no nt).
// ---------------------------------------------------------------------------
__global__ __launch_bounds__(512) void k2_shift_conv2(
    const float* __restrict__ x, const float* __restrict__ fmap,
    const float* __restrict__ ws, float* __restrict__ out) {
  const int tid = threadIdx.x;
  const int G = blockIdx.y;        // group 0..2
  const int lane = tid & 63;
  const int wv = tid >> 6;         // 0..7
  const int q = lane >> 4;
  const int colL = lane & 15;
  const int strip = (blockIdx.x & 7) * 49 + (blockIdx.x >> 3);  // 392 = 8*49

  short8 A0, A1;
  {
    const short8* wf2 = (const short8*)(ws + WS_W2F);
    A0 = wf2[(G * 2 + 0) * 64 + lane];
    A1 = wf2[(G * 2 + 1) * 64 + lane];
  }

  float c2_[8], w00_[8], w01_[8], w10_[8], w11_[8];
  int off_[8], ay_[8], ax_[8];
#pragma unroll
  for (int j = 0; j < 8; ++j) {
    const float* pp = ws + WS_P + (G * 32 + q * 8 + j) * 8;
    c2_[j] = pp[0];
    w00_[j] = pp[1];
    w01_[j] = pp[2];
    w10_[j] = pp[3];
    w11_[j] = pp[4];
    const int ayax = __float_as_int(pp[5]);
    ay_[j] = ayax >> 16;
    ax_[j] = (short)(ayax & 0xffff);
    off_[j] = __float_as_int(pp[6]);
  }

  const int Pw = strip * 256 + wv * 32;   // 32 | 3136: n const per wave
  const int n = Pw / HW;
  const int pw = Pw - n * HW;
  const int cb = n * CC + G * 32;
  const float* fb = fmap + (size_t)cb * HW;
  const float* xb = x + (size_t)cb * HW;
  float* ob = out + (size_t)cb * HW;

#pragma unroll
  for (int t = 0; t < 2; ++t) {
    const int p = pw + t * 16 + colL;
    const int y = p / 56;
    const int xx = p - y * 56;

    // residual prefetch (independent of gather chain)
    float xr0[4], xr1[4];
#pragma unroll
    for (int r = 0; r < 4; ++r) {
      xr0[r] = xb[(size_t)(q * 4 + r) * HW + p];
      xr1[r] = xb[(size_t)(16 + q * 4 + r) * HW + p];
    }

    short8 B;
#pragma unroll
    for (int j = 0; j < 8; ++j) {
      const int ci = q * 8 + j;
      const float* fc = fb + (size_t)ci * HW;
      const int to = p + off_[j];
      float f00 = fc[to];
      float f01 = fc[min(to + 1, HW - 1)];
      float f10 = fc[min(to + 56, HW - 1)];
      float f11 = fc[min(to + 57, HW - 1)];
      float q00 = fmaxf(f00 + c2_[j], 0.f);
      float q01 = fmaxf(f01 + c2_[j], 0.f);
      float q10 = fmaxf(f10 + c2_[j], 0.f);
      float q11 = fmaxf(f11 + c2_[j], 0.f);
      const int yq = y + ay_[j], xq = xx + ax_[j];
      const bool vy0 = yq >= 0, vy1 = yq <= 54;
      const bool vx0 = xq >= 0, vx1 = xq <= 54;
      float h = ((vy0 && vx0) ? w00_[j] : 0.f) * q00;
      h = fmaf(((vy0 && vx1) ? w01_[j] : 0.f), q01, h);
      h = fmaf(((vy1 && vx0) ? w10_[j] : 0.f), q10, h);
      h = fmaf(((vy1 && vx1) ? w11_[j] : 0.f), q11, h);
      __hip_bfloat16 hb = __float2bfloat16(h);
      unsigned short us;
      memcpy(&us, &hb, 2);
      B[j] = (short)us;
    }

    float4_ D0 = {0.f, 0.f, 0.f, 0.f};
    float4_ D1 = {0.f, 0.f, 0.f, 0.f};
    D0 = __builtin_amdgcn_mfma_f32_16x16x32_bf16(A0, B, D0, 0, 0, 0);
    D1 = __builtin_amdgcn_mfma_f32_16x16x32_bf16(A1, B, D1, 0, 0, 0);

#pragma unroll
    for (int r = 0; r < 4; ++r) {
      ob[(size_t)(q * 4 + r) * HW + p] = D0[r] + xr0[r];
      ob[(size_t)(16 + q * 4 + r) * HW + p] = D1[r] + xr1[r];
    }
  }
}

extern "C" void kernel_launch(void* const* d_in, const int* in_sizes, int n_in,
                              void* d_out, int out_size, void* d_ws, size_t ws_size,
                              hipStream_t stream) {
  const float* x     = (const float*)d_in[0];
  const float* prev  = (const float*)d_in[1];
  const float* g1    = (const float*)d_in[2];
  const float* be1   = (const float*)d_in[3];
  const float* m1    = (const float*)d_in[4];
  const float* v1    = (const float*)d_in[5];
  const float* g2    = (const float*)d_in[6];
  const float* be2   = (const float*)d_in[7];
  const float* m2    = (const float*)d_in[8];
  const float* v2    = (const float*)d_in[9];
  const float* w1    = (const float*)d_in[10];
  const float* w2    = (const float*)d_in[11];
  const float* shift = (const float*)d_in[12];

  float* out  = (float*)d_out;
  float* fmap = out + (size_t)NB * CC * HW;  // second output, written in place
  float* ws   = (float*)d_ws;

  precompute_k<<<12, 128, 0, stream>>>(g1, be1, m1, v1, g2, be2, m2, v2,
                                       w1, w2, shift, ws);
  k1_conv1<<<dim3(392, 2), 256, 0, stream>>>(x, prev, ws, fmap);
  k2_shift_conv2<<<dim3(392, 3), 512, 0, stream>>>(x, fmap, ws, out);
}

// Round 15
// 57.236 us; speedup vs baseline: 1.0485x; 1.0485x over previous
//
#include <hip/hip_runtime.h>
#include <hip/hip_bf16.h>
#include <string.h>

// N=32, C=96, H=W=56. HW=3136, NP=100352.
// d_out = [ out (9,633,792 f32) | fmap (9,633,792 f32) ]
//
// ws layout (float index):
//   [   0, 4608) W1 bf16 A-frags: slot ((g*3+m)*3+k)*64+lane (16 B each),
//                w'[o=16m+(lane&15)][ci=32k+(lane>>4)*8+j], w' = w1*s1
//   [4608, 4800) c1[192] f32: c = b1/s1 (act' = max(x + c, 0))
//   [4800, 6336) W2 bf16 A-frags: slot ((G*2+m))*64+lane,
//                w2[o=G*32+16m+(lane&15)][ci=(lane>>4)*8+j]  (no fold)
//   [6336, 7104) p2[96][8]: c2=b2/s2, w00*s2, w01*s2, w10*s2, w11*s2,
//                ayax packed, off = ay*56+ax, pad
#define WSC_OFF 4608
#define WS_W2F  4800
#define WS_P    6336

#define HW 3136
#define CC 96
#define NB 32

typedef __attribute__((ext_vector_type(8))) short short8;
typedef __attribute__((ext_vector_type(4))) float float4_;

__global__ __launch_bounds__(128) void precompute_k(
    const float* __restrict__ g1, const float* __restrict__ be1,
    const float* __restrict__ m1, const float* __restrict__ v1,
    const float* __restrict__ g2, const float* __restrict__ be2,
    const float* __restrict__ m2, const float* __restrict__ v2,
    const float* __restrict__ w1, const float* __restrict__ w2,
    const float* __restrict__ shift, float* __restrict__ ws) {
  const int t = blockIdx.x * 128 + threadIdx.x;  // 12*128 = 1536 threads
  if (t < 192) {
    float s = g1[t] / sqrtf(v1[t] + 1e-5f);
    float b = be1[t] - m1[t] * s;
    ws[WSC_OFF + t] = b / s;     // gamma > 0 guaranteed
  }
  if (t >= 192 && t < 288) {     // conv2 per-channel params (s2 folded into w)
    int c = t - 192;
    float s = g2[c] / sqrtf(v2[c] + 1e-5f);
    float b = be2[c] - m2[c] * s;
    float dy = shift[2 * c], dx = shift[2 * c + 1];
    float fy = floorf(dy), fx = floorf(dx);
    float wy = dy - fy, wx = dx - fx;
    int ay = (int)fy, ax = (int)fx;
    float* pp = ws + WS_P + c * 8;
    pp[0] = b / s;                       // c2: q = s*relu(f + c2)
    pp[1] = (1.f - wy) * (1.f - wx) * s;
    pp[2] = (1.f - wy) * wx * s;
    pp[3] = wy * (1.f - wx) * s;
    pp[4] = wy * wx * s;
    pp[5] = __int_as_float((ay << 16) | (ax & 0xffff));
    pp[6] = __int_as_float(ay * 56 + ax);
    pp[7] = 0.f;
  }
  if (t < 1152) {                // W1 fragments (scale-folded bf16)
    const int lane = t & 63;
    const int gmk = t >> 6;      // 0..17
    const int k = gmk % 3;
    const int gm = gmk / 3;
    const int m = gm % 3;
    const int g = gm / 3;
    const int o = 16 * m + (lane & 15);
    const int ci0 = 32 * k + (lane >> 4) * 8;
    unsigned int pk[4];
    for (int jj = 0; jj < 4; ++jj) {
      unsigned short us[2];
      for (int h = 0; h < 2; ++h) {
        int ci = ci0 + 2 * jj + h;
        float s = g1[g * 96 + ci] / sqrtf(v1[g * 96 + ci] + 1e-5f);
        float w = w1[(g * 48 + o) * 96 + ci] * s;
        __hip_bfloat16 hb = __float2bfloat16(w);
        memcpy(&us[h], &hb, 2);
      }
      pk[jj] = (unsigned int)us[0] | ((unsigned int)us[1] << 16);
    }
    uint4 val;
    val.x = pk[0]; val.y = pk[1]; val.z = pk[2]; val.w = pk[3];
    ((uint4*)ws)[t] = val;
  } else if (t < 1536) {         // W2 fragments (plain bf16)
    const int s2i = t - 1152;    // 0..383
    const int lane = s2i & 63;
    const int gm = s2i >> 6;     // 0..5
    const int m = gm & 1;
    const int G = gm >> 1;
    const int o = G * 32 + m * 16 + (lane & 15);
    const int k0 = (lane >> 4) * 8;
    unsigned int pk[4];
    for (int jj = 0; jj < 4; ++jj) {
      unsigned short us[2];
      for (int h = 0; h < 2; ++h) {
        __hip_bfloat16 hb = __float2bfloat16(w2[o * 32 + k0 + 2 * jj + h]);
        memcpy(&us[h], &hb, 2);
      }
      pk[jj] = (unsigned int)us[0] | ((unsigned int)us[1] << 16);
    }
    uint4 val;
    val.x = pk[0]; val.y = pk[1]; val.z = pk[2]; val.w = pk[3];
    ((uint4*)(ws + WS_W2F))[s2i] = val;
  }
}

// ---------------------------------------------------------------------------
// K1 (MFMA): fmap = conv1x1_g2( bnrelu1( concat ), w1 )
// grid (1568, 2) LINEAR, block 256 = 4 waves; wave = ONE 16-px tile.
// 12,544 short waves -> 32 resident waves/CU (VGPR=56 permits 8/SIMD):
// latency hiding via TLP instead of per-wave ILP (K1 is latency-bound:
// 2.7 TB/s effective vs 7 TB/s streaming; VALUBusy ~26%).
// ---------------------------------------------------------------------------
__global__ __launch_bounds__(256) void k1_conv1(
    const float* __restrict__ x, const float* __restrict__ prev,
    const float* __restrict__ ws, float* __restrict__ fmap) {
  const int tid = threadIdx.x;
  const int lane = tid & 63;
  const int wv = tid >> 6;       // 0..3
  const int g = blockIdx.y;
  const int strip = blockIdx.x;  // linear, 64-px strips
  const int q = lane >> 4;       // 0..3
  const int colL = lane & 15;

  short8 A[3][3];
  const short8* wf = (const short8*)ws;
#pragma unroll
  for (int m = 0; m < 3; ++m)
#pragma unroll
    for (int k = 0; k < 3; ++k)
      A[m][k] = wf[((g * 3 + m) * 3 + k) * 64 + lane];

  float c_[3][8];
#pragma unroll
  for (int k = 0; k < 3; ++k) {
    const float* cp = ws + WSC_OFF + g * 96 + 32 * k + 8 * q;
#pragma unroll
    for (int j = 0; j < 8; ++j) c_[k][j] = cp[j];
  }

  const int P = strip * 64 + wv * 16;     // 64 | 3136: n const per strip
  const int n = P / HW;
  const int p = P - n * HW;
  const size_t nb = (size_t)n * CC * HW;
  const int col = p + colL;

  // per-k source base (octets never straddle the x/prev split)
  const float* sb[3];
#pragma unroll
  for (int k = 0; k < 3; ++k) {
    const int ci0 = 32 * k + 8 * q;
    sb[k] = (ci0 < 48)
        ? (x + nb + (size_t)(g * 48 + ci0) * HW)
        : (prev + nb + (size_t)((1 - g) * 48 + (ci0 - 48)) * HW);
  }
  float* fb = fmap + nb + (size_t)(g * 48) * HW;

  float4_ D[3] = {{0.f, 0.f, 0.f, 0.f}, {0.f, 0.f, 0.f, 0.f},
                  {0.f, 0.f, 0.f, 0.f}};
#pragma unroll
  for (int k = 0; k < 3; ++k) {
    float a[8];
#pragma unroll
    for (int j = 0; j < 8; ++j) a[j] = sb[k][(size_t)j * HW + col];
    short8 B;
#pragma unroll
    for (int j = 0; j < 8; ++j) {
      float f = fmaxf(a[j] + c_[k][j], 0.f);
      __hip_bfloat16 hb = __float2bfloat16(f);
      unsigned short us;
      memcpy(&us, &hb, 2);
      B[j] = (short)us;
    }
#pragma unroll
    for (int m = 0; m < 3; ++m)
      D[m] = __builtin_amdgcn_mfma_f32_16x16x32_bf16(A[m][k], B, D[m],
                                                     0, 0, 0);
  }
#pragma unroll
  for (int m = 0; m < 3; ++m)
#pragma unroll
    for (int r = 0; r < 4; ++r)
      fb[(size_t)(16 * m + q * 4 + r) * HW + col] = D[m][r];
}

// ---------------------------------------------------------------------------
// K2 (MFMA): out = conv1x1_g3( active_shift( bnrelu2(fmap) ), w2 ) + x
// grid (784, 3) LINEAR, 128-px strips; block 256 = 4 waves; wave = 2 tiles.
// s2 folded into tap weights. (r13's exact kernel — best-total config.)
// ---------------------------------------------------------------------------
__global__ __launch_bounds__(256) void k2_shift_conv2(
    const float* __restrict__ x, const float* __restrict__ fmap,
    const float* __restrict__ ws, float* __restrict__ out) {
  const int tid = threadIdx.x;
  const int G = blockIdx.y;        // group 0..2
  const int lane = tid & 63;
  const int wv = tid >> 6;         // 0..3
  const int q = lane >> 4;
  const int colL = lane & 15;
  const int strip = blockIdx.x;    // linear, same px order as K1

  short8 A0, A1;
  {
    const short8* wf2 = (const short8*)(ws + WS_W2F);
    A0 = wf2[(G * 2 + 0) * 64 + lane];
    A1 = wf2[(G * 2 + 1) * 64 + lane];
  }

  float c2_[8], w00_[8], w01_[8], w10_[8], w11_[8];
  int off_[8], ay_[8], ax_[8];
#pragma unroll
  for (int j = 0; j < 8; ++j) {
    const float* pp = ws + WS_P + (G * 32 + q * 8 + j) * 8;
    c2_[j] = pp[0];
    w00_[j] = pp[1];
    w01_[j] = pp[2];
    w10_[j] = pp[3];
    w11_[j] = pp[4];
    const int ayax = __float_as_int(pp[5]);
    ay_[j] = ayax >> 16;
    ax_[j] = (short)(ayax & 0xffff);
    off_[j] = __float_as_int(pp[6]);
  }

  const int Pw = strip * 128 + wv * 32;   // 32 | 3136: n const per wave
  const int n = Pw / HW;
  const int pw = Pw - n * HW;
  const int cb = n * CC + G * 32;
  const float* fb = fmap + (size_t)cb * HW;
  const float* xb = x + (size_t)cb * HW;
  float* ob = out + (size_t)cb * HW;

#pragma unroll
  for (int t = 0; t < 2; ++t) {
    const int p = pw + t * 16 + colL;
    const int y = p / 56;
    const int xx = p - y * 56;

    // residual prefetch (independent of gather chain)
    float xr0[4], xr1[4];
#pragma unroll
    for (int r = 0; r < 4; ++r) {
      xr0[r] = xb[(size_t)(q * 4 + r) * HW + p];
      xr1[r] = xb[(size_t)(16 + q * 4 + r) * HW + p];
    }

    short8 B;
#pragma unroll
    for (int j = 0; j < 8; ++j) {
      const int ci = q * 8 + j;
      const float* fc = fb + (size_t)ci * HW;
      const int to = p + off_[j];
      float f00 = fc[to];
      float f01 = fc[min(to + 1, HW - 1)];
      float f10 = fc[min(to + 56, HW - 1)];
      float f11 = fc[min(to + 57, HW - 1)];
      float q00 = fmaxf(f00 + c2_[j], 0.f);
      float q01 = fmaxf(f01 + c2_[j], 0.f);
      float q10 = fmaxf(f10 + c2_[j], 0.f);
      float q11 = fmaxf(f11 + c2_[j], 0.f);
      const int yq = y + ay_[j], xq = xx + ax_[j];
      const bool vy0 = yq >= 0, vy1 = yq <= 54;
      const bool vx0 = xq >= 0, vx1 = xq <= 54;
      float h = ((vy0 && vx0) ? w00_[j] : 0.f) * q00;
      h = fmaf(((vy0 && vx1) ? w01_[j] : 0.f), q01, h);
      h = fmaf(((vy1 && vx0) ? w10_[j] : 0.f), q10, h);
      h = fmaf(((vy1 && vx1) ? w11_[j] : 0.f), q11, h);
      __hip_bfloat16 hb = __float2bfloat16(h);
      unsigned short us;
      memcpy(&us, &hb, 2);
      B[j] = (short)us;
    }

    float4_ D0 = {0.f, 0.f, 0.f, 0.f};
    float4_ D1 = {0.f, 0.f, 0.f, 0.f};
    D0 = __builtin_amdgcn_mfma_f32_16x16x32_bf16(A0, B, D0, 0, 0, 0);
    D1 = __builtin_amdgcn_mfma_f32_16x16x32_bf16(A1, B, D1, 0, 0, 0);

#pragma unroll
    for (int r = 0; r < 4; ++r) {
      ob[(size_t)(q * 4 + r) * HW + p] = D0[r] + xr0[r];
      ob[(size_t)(16 + q * 4 + r) * HW + p] = D1[r] + xr1[r];
    }
  }
}

extern "C" void kernel_launch(void* const* d_in, const int* in_sizes, int n_in,
                              void* d_out, int out_size, void* d_ws, size_t ws_size,
                              hipStream_t stream) {
  const float* x     = (const float*)d_in[0];
  const float* prev  = (const float*)d_in[1];
  const float* g1    = (const float*)d_in[2];
  const float* be1   = (const float*)d_in[3];
  const float* m1    = (const float*)d_in[4];
  const float* v1    = (const float*)d_in[5];
  const float* g2    = (const float*)d_in[6];
  const float* be2   = (const float*)d_in[7];
  const float* m2    = (const float*)d_in[8];
  const float* v2    = (const float*)d_in[9];
  const float* w1    = (const float*)d_in[10];
  const float* w2    = (const float*)d_in[11];
  const float* shift = (const float*)d_in[12];

  float* out  = (float*)d_out;
  float* fmap = out + (size_t)NB * CC * HW;  // second output, written in place
  float* ws   = (float*)d_ws;

  precompute_k<<<12, 128, 0, stream>>>(g1, be1, m1, v1, g2, be2, m2, v2,
                                       w1, w2, shift, ws);
  k1_conv1<<<dim3(1568, 2), 256, 0, stream>>>(x, prev, ws, fmap);
  k2_shift_conv2<<<dim3(784, 3), 256, 0, stream>>>(x, fmap, ws, out);
}

// Round 16
// 56.747 us; speedup vs baseline: 1.0575x; 1.0086x over previous
//
#include <hip/hip_runtime.h>
#include <hip/hip_bf16.h>
#include <string.h>

// N=32, C=96, H=W=56. HW=3136, NP=100352.
// d_out = [ out (9,633,792 f32) | fmap (9,633,792 f32) ]
//
// ws layout (float index):
//   [   0, 4608) W1 bf16 A-frags: slot ((g*3+m)*3+k)*64+lane (16 B each),
//                w'[o=16m+(lane&15)][ci=32k+(lane>>4)*8+j], w' = w1*s1
//   [4608, 4800) c1[192] f32: c = b1/s1 (act' = max(x + c, 0))
//   [4800, 6336) W2 bf16 A-frags: slot ((G*2+m))*64+lane,
//                w2[o=G*32+16m+(lane&15)][ci=(lane>>4)*8+j]  (no fold)
//   [6336, 7104) p2[96][8]: c2=b2/s2, w00*s2, w01*s2, w10*s2, w11*s2,
//                ayax packed, off = ay*56+ax, pad
#define WSC_OFF 4608
#define WS_W2F  4800
#define WS_P    6336

#define HW 3136
#define CC 96
#define NB 32
#define LST 66   // LDS row stride (floats): 8B-aligned rows, 2-way-free banks

typedef __attribute__((ext_vector_type(8))) short short8;
typedef __attribute__((ext_vector_type(4))) float float4_;

__global__ __launch_bounds__(128) void precompute_k(
    const float* __restrict__ g1, const float* __restrict__ be1,
    const float* __restrict__ m1, const float* __restrict__ v1,
    const float* __restrict__ g2, const float* __restrict__ be2,
    const float* __restrict__ m2, const float* __restrict__ v2,
    const float* __restrict__ w1, const float* __restrict__ w2,
    const float* __restrict__ shift, float* __restrict__ ws) {
  const int t = blockIdx.x * 128 + threadIdx.x;  // 12*128 = 1536 threads
  if (t < 192) {
    float s = g1[t] / sqrtf(v1[t] + 1e-5f);
    float b = be1[t] - m1[t] * s;
    ws[WSC_OFF + t] = b / s;     // gamma > 0 guaranteed
  }
  if (t >= 192 && t < 288) {     // conv2 per-channel params (s2 folded into w)
    int c = t - 192;
    float s = g2[c] / sqrtf(v2[c] + 1e-5f);
    float b = be2[c] - m2[c] * s;
    float dy = shift[2 * c], dx = shift[2 * c + 1];
    float fy = floorf(dy), fx = floorf(dx);
    float wy = dy - fy, wx = dx - fx;
    int ay = (int)fy, ax = (int)fx;
    float* pp = ws + WS_P + c * 8;
    pp[0] = b / s;                       // c2: q = s*relu(f + c2)
    pp[1] = (1.f - wy) * (1.f - wx) * s;
    pp[2] = (1.f - wy) * wx * s;
    pp[3] = wy * (1.f - wx) * s;
    pp[4] = wy * wx * s;
    pp[5] = __int_as_float((ay << 16) | (ax & 0xffff));
    pp[6] = __int_as_float(ay * 56 + ax);
    pp[7] = 0.f;
  }
  if (t < 1152) {                // W1 fragments (scale-folded bf16)
    const int lane = t & 63;
    const int gmk = t >> 6;      // 0..17
    const int k = gmk % 3;
    const int gm = gmk / 3;
    const int m = gm % 3;
    const int g = gm / 3;
    const int o = 16 * m + (lane & 15);
    const int ci0 = 32 * k + (lane >> 4) * 8;
    unsigned int pk[4];
    for (int jj = 0; jj < 4; ++jj) {
      unsigned short us[2];
      for (int h = 0; h < 2; ++h) {
        int ci = ci0 + 2 * jj + h;
        float s = g1[g * 96 + ci] / sqrtf(v1[g * 96 + ci] + 1e-5f);
        float w = w1[(g * 48 + o) * 96 + ci] * s;
        __hip_bfloat16 hb = __float2bfloat16(w);
        memcpy(&us[h], &hb, 2);
      }
      pk[jj] = (unsigned int)us[0] | ((unsigned int)us[1] << 16);
    }
    uint4 val;
    val.x = pk[0]; val.y = pk[1]; val.z = pk[2]; val.w = pk[3];
    ((uint4*)ws)[t] = val;
  } else if (t < 1536) {         // W2 fragments (plain bf16)
    const int s2i = t - 1152;    // 0..383
    const int lane = s2i & 63;
    const int gm = s2i >> 6;     // 0..5
    const int m = gm & 1;
    const int G = gm >> 1;
    const int o = G * 32 + m * 16 + (lane & 15);
    const int k0 = (lane >> 4) * 8;
    unsigned int pk[4];
    for (int jj = 0; jj < 4; ++jj) {
      unsigned short us[2];
      for (int h = 0; h < 2; ++h) {
        __hip_bfloat16 hb = __float2bfloat16(w2[o * 32 + k0 + 2 * jj + h]);
        memcpy(&us[h], &hb, 2);
      }
      pk[jj] = (unsigned int)us[0] | ((unsigned int)us[1] << 16);
    }
    uint4 val;
    val.x = pk[0]; val.y = pk[1]; val.z = pk[2]; val.w = pk[3];
    ((uint4*)(ws + WS_W2F))[s2i] = val;
  }
}

// ---------------------------------------------------------------------------
// K1 (MFMA, LDS-staged): fmap = conv1x1_g2( bnrelu1( concat ), w1 )
// grid (1568, 2): 64-px strip x group; block 256 = 4 waves.
// Stage: 96 ch x 64 px loaded as dense per-channel float4 runs (6/thread,
// fully coalesced), relu(x + c1) applied in-stage, f32 -> LDS [96][66].
// Compute: wave = one 16-px tile; B-frags from LDS (b32, 2-way-free banks),
// 9 MFMA; scattered fmap stores (fire-and-forget).
// Rationale: previous K1 was latency-bound (~1800 cyc/wave: 3 serialized
// 8-load batches of 4x64B scattered segments; VGPR=56 allowed no more ILP).
// Dense staged reads remove the per-wave latency chains.
// ---------------------------------------------------------------------------
__global__ __launch_bounds__(256) void k1_conv1(
    const float* __restrict__ x, const float* __restrict__ prev,
    const float* __restrict__ ws, float* __restrict__ fmap) {
  __shared__ float sA[96 * LST];   // 25,344 B

  const int tid = threadIdx.x;
  const int g = blockIdx.y;
  const int strip = blockIdx.x;    // 0..1567, 64 px each
  const int P0 = strip * 64;       // 64 | 3136: whole block in one image
  const int n = P0 / HW;
  const int p0 = P0 - n * HW;
  const size_t nb = (size_t)n * CC * HW;

  const int lane = tid & 63;
  const int wv = tid >> 6;         // 0..3: px tile
  const int q = lane >> 4;         // 0..3
  const int colL = lane & 15;

  // weight fragments (independent of stage; scheduler overlaps)
  short8 A[3][3];
  const short8* wf = (const short8*)ws;
#pragma unroll
  for (int m = 0; m < 3; ++m)
#pragma unroll
    for (int k = 0; k < 3; ++k)
      A[m][k] = wf[((g * 3 + m) * 3 + k) * 64 + lane];

  // ---- stage ----
  const float* cbase = ws + WSC_OFF + g * 96;
#pragma unroll
  for (int i = 0; i < 6; ++i) {
    const int idx = i * 256 + tid;  // 0..1535
    const int row = idx >> 4;       // channel 0..95
    const int px4 = idx & 15;
    const float* src = (row < 48)
        ? (x + nb + (size_t)(g * 48 + row) * HW)
        : (prev + nb + (size_t)((1 - g) * 48 + (row - 48)) * HW);
    const float c = cbase[row];
    const float4 v = *reinterpret_cast<const float4*>(src + p0 + px4 * 4);
    float* d = &sA[row * LST + px4 * 4];
    reinterpret_cast<float2*>(d)[0] =
        make_float2(fmaxf(v.x + c, 0.f), fmaxf(v.y + c, 0.f));
    reinterpret_cast<float2*>(d)[1] =
        make_float2(fmaxf(v.z + c, 0.f), fmaxf(v.w + c, 0.f));
  }
  __syncthreads();

  // ---- compute ----
  const int px = wv * 16 + colL;
  float4_ D[3] = {{0.f, 0.f, 0.f, 0.f}, {0.f, 0.f, 0.f, 0.f},
                  {0.f, 0.f, 0.f, 0.f}};
#pragma unroll
  for (int k = 0; k < 3; ++k) {
    const float* lp = &sA[(32 * k + 8 * q) * LST + px];
    short8 B;
#pragma unroll
    for (int j = 0; j < 8; ++j) {
      float f = lp[j * LST];
      __hip_bfloat16 hb = __float2bfloat16(f);
      unsigned short us;
      memcpy(&us, &hb, 2);
      B[j] = (short)us;
    }
#pragma unroll
    for (int m = 0; m < 3; ++m)
      D[m] = __builtin_amdgcn_mfma_f32_16x16x32_bf16(A[m][k], B, D[m],
                                                     0, 0, 0);
  }

  const int col = p0 + px;
  float* fb = fmap + nb + (size_t)(g * 48) * HW;
#pragma unroll
  for (int m = 0; m < 3; ++m)
#pragma unroll
    for (int r = 0; r < 4; ++r)
      fb[(size_t)(16 * m + q * 4 + r) * HW + col] = D[m][r];
}

// ---------------------------------------------------------------------------
// K2 (MFMA): out = conv1x1_g3( active_shift( bnrelu2(fmap) ), w2 ) + x
// grid (784, 3) LINEAR, 128-px strips; block 256 = 4 waves; wave = 2 tiles.
// s2 folded into tap weights. (r15's exact kernel.)
// ---------------------------------------------------------------------------
__global__ __launch_bounds__(256) void k2_shift_conv2(
    const float* __restrict__ x, const float* __restrict__ fmap,
    const float* __restrict__ ws, float* __restrict__ out) {
  const int tid = threadIdx.x;
  const int G = blockIdx.y;        // group 0..2
  const int lane = tid & 63;
  const int wv = tid >> 6;         // 0..3
  const int q = lane >> 4;
  const int colL = lane & 15;
  const int strip = blockIdx.x;    // linear, same px order as K1

  short8 A0, A1;
  {
    const short8* wf2 = (const short8*)(ws + WS_W2F);
    A0 = wf2[(G * 2 + 0) * 64 + lane];
    A1 = wf2[(G * 2 + 1) * 64 + lane];
  }

  float c2_[8], w00_[8], w01_[8], w10_[8], w11_[8];
  int off_[8], ay_[8], ax_[8];
#pragma unroll
  for (int j = 0; j < 8; ++j) {
    const float* pp = ws + WS_P + (G * 32 + q * 8 + j) * 8;
    c2_[j] = pp[0];
    w00_[j] = pp[1];
    w01_[j] = pp[2];
    w10_[j] = pp[3];
    w11_[j] = pp[4];
    const int ayax = __float_as_int(pp[5]);
    ay_[j] = ayax >> 16;
    ax_[j] = (short)(ayax & 0xffff);
    off_[j] = __float_as_int(pp[6]);
  }

  const int Pw = strip * 128 + wv * 32;   // 32 | 3136: n const per wave
  const int n = Pw / HW;
  const int pw = Pw - n * HW;
  const int cb = n * CC + G * 32;
  const float* fb = fmap + (size_t)cb * HW;
  const float* xb = x + (size_t)cb * HW;
  float* ob = out + (size_t)cb * HW;

#pragma unroll
  for (int t = 0; t < 2; ++t) {
    const int p = pw + t * 16 + colL;
    const int y = p / 56;
    const int xx = p - y * 56;

    // residual prefetch (independent of gather chain)
    float xr0[4], xr1[4];
#pragma unroll
    for (int r = 0; r < 4; ++r) {
      xr0[r] = xb[(size_t)(q * 4 + r) * HW + p];
      xr1[r] = xb[(size_t)(16 + q * 4 + r) * HW + p];
    }

    short8 B;
#pragma unroll
    for (int j = 0; j < 8; ++j) {
      const int ci = q * 8 + j;
      const float* fc = fb + (size_t)ci * HW;
      const int to = p + off_[j];
      float f00 = fc[to];
      float f01 = fc[min(to + 1, HW - 1)];
      float f10 = fc[min(to + 56, HW - 1)];
      float f11 = fc[min(to + 57, HW - 1)];
      float q00 = fmaxf(f00 + c2_[j], 0.f);
      float q01 = fmaxf(f01 + c2_[j], 0.f);
      float q10 = fmaxf(f10 + c2_[j], 0.f);
      float q11 = fmaxf(f11 + c2_[j], 0.f);
      const int yq = y + ay_[j], xq = xx + ax_[j];
      const bool vy0 = yq >= 0, vy1 = yq <= 54;
      const bool vx0 = xq >= 0, vx1 = xq <= 54;
      float h = ((vy0 && vx0) ? w00_[j] : 0.f) * q00;
      h = fmaf(((vy0 && vx1) ? w01_[j] : 0.f), q01, h);
      h = fmaf(((vy1 && vx0) ? w10_[j] : 0.f), q10, h);
      h = fmaf(((vy1 && vx1) ? w11_[j] : 0.f), q11, h);
      __hip_bfloat16 hb = __float2bfloat16(h);
      unsigned short us;
      memcpy(&us, &hb, 2);
      B[j] = (short)us;
    }

    float4_ D0 = {0.f, 0.f, 0.f, 0.f};
    float4_ D1 = {0.f, 0.f, 0.f, 0.f};
    D0 = __builtin_amdgcn_mfma_f32_16x16x32_bf16(A0, B, D0, 0, 0, 0);
    D1 = __builtin_amdgcn_mfma_f32_16x16x32_bf16(A1, B, D1, 0, 0, 0);

#pragma unroll
    for (int r = 0; r < 4; ++r) {
      ob[(size_t)(q * 4 + r) * HW + p] = D0[r] + xr0[r];
      ob[(size_t)(16 + q * 4 + r) * HW + p] = D1[r] + xr1[r];
    }
  }
}

extern "C" void kernel_launch(void* const* d_in, const int* in_sizes, int n_in,
                              void* d_out, int out_size, void* d_ws, size_t ws_size,
                              hipStream_t stream) {
  const float* x     = (const float*)d_in[0];
  const float* prev  = (const float*)d_in[1];
  const float* g1    = (const float*)d_in[2];
  const float* be1   = (const float*)d_in[3];
  const float* m1    = (const float*)d_in[4];
  const float* v1    = (const float*)d_in[5];
  const float* g2    = (const float*)d_in[6];
  const float* be2   = (const float*)d_in[7];
  const float* m2    = (const float*)d_in[8];
  const float* v2    = (const float*)d_in[9];
  const float* w1    = (const float*)d_in[10];
  const float* w2    = (const float*)d_in[11];
  const float* shift = (const float*)d_in[12];

  float* out  = (float*)d_out;
  float* fmap = out + (size_t)NB * CC * HW;  // second output, written in place
  float* ws   = (float*)d_ws;

  precompute_k<<<12, 128, 0, stream>>>(g1, be1, m1, v1, g2, be2, m2, v2,
                                       w1, w2, shift, ws);
  k1_conv1<<<dim3(1568, 2), 256, 0, stream>>>(x, prev, ws, fmap);
  k2_shift_conv2<<<dim3(784, 3), 256, 0, stream>>>(x, fmap, ws, out);
}

// Round 17
// 53.995 us; speedup vs baseline: 1.1114x; 1.0510x over previous
//
#include <hip/hip_runtime.h>
#include <hip/hip_bf16.h>
#include <string.h>

// N=32, C=96, H=W=56. HW=3136, NP=100352.
// d_out = [ out (9,633,792 f32) | fmap (9,633,792 f32) ]
//
// ws layout (float index):
//   [   0, 4608) W1 bf16 A-frags: slot ((g*3+m)*3+k)*64+lane (16 B each),
//                w'[o=16m+(lane&15)][ci=32k+(lane>>4)*8+j], w' = w1*s1
//   [4608, 4800) c1[192] f32: c = b1/s1 (act' = max(x + c, 0))
//   [4800, 6336) W2 bf16 A-frags: slot ((G*2+m))*64+lane,
//                w2[o=G*32+16m+(lane&15)][ci=(lane>>4)*8+j]  (no fold)
//   [6336, 7104) p2[96][8]: c2=b2/s2, w00*s2, w01*s2, w10*s2, w11*s2,
//                ayax packed, off = ay*56+ax, pad
#define WSC_OFF 4608
#define WS_W2F  4800
#define WS_P    6336

#define HW 3136
#define CC 96
#define NB 32
#define LST 66   // K1 LDS row stride (floats)
#define OST 34   // K2 per-wave out-stage row stride (floats)

typedef __attribute__((ext_vector_type(8))) short short8;
typedef __attribute__((ext_vector_type(4))) float float4_;

__global__ __launch_bounds__(128) void precompute_k(
    const float* __restrict__ g1, const float* __restrict__ be1,
    const float* __restrict__ m1, const float* __restrict__ v1,
    const float* __restrict__ g2, const float* __restrict__ be2,
    const float* __restrict__ m2, const float* __restrict__ v2,
    const float* __restrict__ w1, const float* __restrict__ w2,
    const float* __restrict__ shift, float* __restrict__ ws) {
  const int t = blockIdx.x * 128 + threadIdx.x;  // 12*128 = 1536 threads
  if (t < 192) {
    float s = g1[t] / sqrtf(v1[t] + 1e-5f);
    float b = be1[t] - m1[t] * s;
    ws[WSC_OFF + t] = b / s;     // gamma > 0 guaranteed
  }
  if (t >= 192 && t < 288) {     // conv2 per-channel params (s2 folded into w)
    int c = t - 192;
    float s = g2[c] / sqrtf(v2[c] + 1e-5f);
    float b = be2[c] - m2[c] * s;
    float dy = shift[2 * c], dx = shift[2 * c + 1];
    float fy = floorf(dy), fx = floorf(dx);
    float wy = dy - fy, wx = dx - fx;
    int ay = (int)fy, ax = (int)fx;
    float* pp = ws + WS_P + c * 8;
    pp[0] = b / s;                       // c2: q = s*relu(f + c2)
    pp[1] = (1.f - wy) * (1.f - wx) * s;
    pp[2] = (1.f - wy) * wx * s;
    pp[3] = wy * (1.f - wx) * s;
    pp[4] = wy * wx * s;
    pp[5] = __int_as_float((ay << 16) | (ax & 0xffff));
    pp[6] = __int_as_float(ay * 56 + ax);
    pp[7] = 0.f;
  }
  if (t < 1152) {                // W1 fragments (scale-folded bf16)
    const int lane = t & 63;
    const int gmk = t >> 6;      // 0..17
    const int k = gmk % 3;
    const int gm = gmk / 3;
    const int m = gm % 3;
    const int g = gm / 3;
    const int o = 16 * m + (lane & 15);
    const int ci0 = 32 * k + (lane >> 4) * 8;
    unsigned int pk[4];
    for (int jj = 0; jj < 4; ++jj) {
      unsigned short us[2];
      for (int h = 0; h < 2; ++h) {
        int ci = ci0 + 2 * jj + h;
        float s = g1[g * 96 + ci] / sqrtf(v1[g * 96 + ci] + 1e-5f);
        float w = w1[(g * 48 + o) * 96 + ci] * s;
        __hip_bfloat16 hb = __float2bfloat16(w);
        memcpy(&us[h], &hb, 2);
      }
      pk[jj] = (unsigned int)us[0] | ((unsigned int)us[1] << 16);
    }
    uint4 val;
    val.x = pk[0]; val.y = pk[1]; val.z = pk[2]; val.w = pk[3];
    ((uint4*)ws)[t] = val;
  } else if (t < 1536) {         // W2 fragments (plain bf16)
    const int s2i = t - 1152;    // 0..383
    const int lane = s2i & 63;
    const int gm = s2i >> 6;     // 0..5
    const int m = gm & 1;
    const int G = gm >> 1;
    const int o = G * 32 + m * 16 + (lane & 15);
    const int k0 = (lane >> 4) * 8;
    unsigned int pk[4];
    for (int jj = 0; jj < 4; ++jj) {
      unsigned short us[2];
      for (int h = 0; h < 2; ++h) {
        __hip_bfloat16 hb = __float2bfloat16(w2[o * 32 + k0 + 2 * jj + h]);
        memcpy(&us[h], &hb, 2);
      }
      pk[jj] = (unsigned int)us[0] | ((unsigned int)us[1] << 16);
    }
    uint4 val;
    val.x = pk[0]; val.y = pk[1]; val.z = pk[2]; val.w = pk[3];
    ((uint4*)(ws + WS_W2F))[s2i] = val;
  }
}

// ---------------------------------------------------------------------------
// K1 (MFMA, staged in AND out): fmap = conv1x1_g2( bnrelu1( concat ), w1 )
// grid (1568, 2): 64-px strip x group; block 256 = 4 waves.
// Stage-in: dense per-channel float4 runs -> LDS [96][66] with relu(x+c).
// Compute: wave = one 16-px tile, 9 MFMA.
// Stage-out: D -> LDS [48][66] -> dense per-channel 256 B float4 runs.
// Rationale: FETCH ~= WRITE across all profiled rounds => 64 B partial-line
// stores caused L2 write-allocate HBM fills. Full-line writes remove them.
// ---------------------------------------------------------------------------
__global__ __launch_bounds__(256) void k1_conv1(
    const float* __restrict__ x, const float* __restrict__ prev,
    const float* __restrict__ ws, float* __restrict__ fmap) {
  __shared__ float sA[96 * LST];   // 25,344 B (reused for out-stage)

  const int tid = threadIdx.x;
  const int g = blockIdx.y;
  const int strip = blockIdx.x;    // 0..1567, 64 px each
  const int P0 = strip * 64;       // 64 | 3136: whole block in one image
  const int n = P0 / HW;
  const int p0 = P0 - n * HW;
  const size_t nb = (size_t)n * CC * HW;

  const int lane = tid & 63;
  const int wv = tid >> 6;         // 0..3: px tile
  const int q = lane >> 4;         // 0..3
  const int colL = lane & 15;

  short8 A[3][3];
  const short8* wf = (const short8*)ws;
#pragma unroll
  for (int m = 0; m < 3; ++m)
#pragma unroll
    for (int k = 0; k < 3; ++k)
      A[m][k] = wf[((g * 3 + m) * 3 + k) * 64 + lane];

  // ---- stage in ----
  const float* cbase = ws + WSC_OFF + g * 96;
#pragma unroll
  for (int i = 0; i < 6; ++i) {
    const int idx = i * 256 + tid;  // 0..1535
    const int row = idx >> 4;       // channel 0..95
    const int px4 = idx & 15;
    const float* src = (row < 48)
        ? (x + nb + (size_t)(g * 48 + row) * HW)
        : (prev + nb + (size_t)((1 - g) * 48 + (row - 48)) * HW);
    const float c = cbase[row];
    const float4 v = *reinterpret_cast<const float4*>(src + p0 + px4 * 4);
    float* d = &sA[row * LST + px4 * 4];
    reinterpret_cast<float2*>(d)[0] =
        make_float2(fmaxf(v.x + c, 0.f), fmaxf(v.y + c, 0.f));
    reinterpret_cast<float2*>(d)[1] =
        make_float2(fmaxf(v.z + c, 0.f), fmaxf(v.w + c, 0.f));
  }
  __syncthreads();

  // ---- compute ----
  const int px = wv * 16 + colL;
  float4_ D[3] = {{0.f, 0.f, 0.f, 0.f}, {0.f, 0.f, 0.f, 0.f},
                  {0.f, 0.f, 0.f, 0.f}};
#pragma unroll
  for (int k = 0; k < 3; ++k) {
    const float* lp = &sA[(32 * k + 8 * q) * LST + px];
    short8 B;
#pragma unroll
    for (int j = 0; j < 8; ++j) {
      float f = lp[j * LST];
      __hip_bfloat16 hb = __float2bfloat16(f);
      unsigned short us;
      memcpy(&us, &hb, 2);
      B[j] = (short)us;
    }
#pragma unroll
    for (int m = 0; m < 3; ++m)
      D[m] = __builtin_amdgcn_mfma_f32_16x16x32_bf16(A[m][k], B, D[m],
                                                     0, 0, 0);
  }
  __syncthreads();   // all sA reads done before overwrite

  // ---- stage out ----
#pragma unroll
  for (int m = 0; m < 3; ++m)
#pragma unroll
    for (int r = 0; r < 4; ++r)
      sA[(16 * m + 4 * q + r) * LST + px] = D[m][r];
  __syncthreads();

  // ---- dense store: 48 ch x 256 B full-line runs ----
  float* fb = fmap + nb + (size_t)(g * 48) * HW;
#pragma unroll
  for (int i = 0; i < 3; ++i) {
    const int idx = i * 256 + tid;  // 0..767
    const int row = idx >> 4;       // 0..47
    const int px4 = idx & 15;
    const float* sp = &sA[row * LST + px4 * 4];
    float2 v0 = reinterpret_cast<const float2*>(sp)[0];
    float2 v1 = reinterpret_cast<const float2*>(sp)[1];
    float4 v = make_float4(v0.x, v0.y, v1.x, v1.y);
    *reinterpret_cast<float4*>(fb + (size_t)row * HW + p0 + px4 * 4) = v;
  }
}

// ---------------------------------------------------------------------------
// K2 (MFMA): out = conv1x1_g3( active_shift( bnrelu2(fmap) ), w2 ) + x
// grid (784, 3) LINEAR, 128-px strips; block 256 = 4 waves; wave = 2 tiles.
// s2 folded into tap weights. NEW: per-wave LDS out-staging -> dense
// 128 B-per-channel float4 stores (kills write-allocate fetches; FETCH was
// ~= WRITE = 45 MB on this kernel).
// ---------------------------------------------------------------------------
__global__ __launch_bounds__(256) void k2_shift_conv2(
    const float* __restrict__ x, const float* __restrict__ fmap,
    const float* __restrict__ ws, float* __restrict__ out) {
  __shared__ float sO[4][32 * OST];   // 4 waves x 4352 B = 17,408 B

  const int tid = threadIdx.x;
  const int G = blockIdx.y;        // group 0..2
  const int lane = tid & 63;
  const int wv = tid >> 6;         // 0..3
  const int q = lane >> 4;
  const int colL = lane & 15;
  const int strip = blockIdx.x;    // linear, same px order as K1

  short8 A0, A1;
  {
    const short8* wf2 = (const short8*)(ws + WS_W2F);
    A0 = wf2[(G * 2 + 0) * 64 + lane];
    A1 = wf2[(G * 2 + 1) * 64 + lane];
  }

  float c2_[8], w00_[8], w01_[8], w10_[8], w11_[8];
  int off_[8], ay_[8], ax_[8];
#pragma unroll
  for (int j = 0; j < 8; ++j) {
    const float* pp = ws + WS_P + (G * 32 + q * 8 + j) * 8;
    c2_[j] = pp[0];
    w00_[j] = pp[1];
    w01_[j] = pp[2];
    w10_[j] = pp[3];
    w11_[j] = pp[4];
    const int ayax = __float_as_int(pp[5]);
    ay_[j] = ayax >> 16;
    ax_[j] = (short)(ayax & 0xffff);
    off_[j] = __float_as_int(pp[6]);
  }

  const int Pw = strip * 128 + wv * 32;   // 32 | 3136: n const per wave
  const int n = Pw / HW;
  const int pw = Pw - n * HW;
  const int cb = n * CC + G * 32;
  const float* fb = fmap + (size_t)cb * HW;
  const float* xb = x + (size_t)cb * HW;
  float* ob = out + (size_t)cb * HW;
  float* so = &sO[wv][0];

#pragma unroll
  for (int t = 0; t < 2; ++t) {
    const int p = pw + t * 16 + colL;
    const int y = p / 56;
    const int xx = p - y * 56;

    // residual prefetch (independent of gather chain)
    float xr0[4], xr1[4];
#pragma unroll
    for (int r = 0; r < 4; ++r) {
      xr0[r] = xb[(size_t)(q * 4 + r) * HW + p];
      xr1[r] = xb[(size_t)(16 + q * 4 + r) * HW + p];
    }

    short8 B;
#pragma unroll
    for (int j = 0; j < 8; ++j) {
      const int ci = q * 8 + j;
      const float* fc = fb + (size_t)ci * HW;
      const int to = p + off_[j];
      float f00 = fc[to];
      float f01 = fc[min(to + 1, HW - 1)];
      float f10 = fc[min(to + 56, HW - 1)];
      float f11 = fc[min(to + 57, HW - 1)];
      float q00 = fmaxf(f00 + c2_[j], 0.f);
      float q01 = fmaxf(f01 + c2_[j], 0.f);
      float q10 = fmaxf(f10 + c2_[j], 0.f);
      float q11 = fmaxf(f11 + c2_[j], 0.f);
      const int yq = y + ay_[j], xq = xx + ax_[j];
      const bool vy0 = yq >= 0, vy1 = yq <= 54;
      const bool vx0 = xq >= 0, vx1 = xq <= 54;
      float h = ((vy0 && vx0) ? w00_[j] : 0.f) * q00;
      h = fmaf(((vy0 && vx1) ? w01_[j] : 0.f), q01, h);
      h = fmaf(((vy1 && vx0) ? w10_[j] : 0.f), q10, h);
      h = fmaf(((vy1 && vx1) ? w11_[j] : 0.f), q11, h);
      __hip_bfloat16 hb = __float2bfloat16(h);
      unsigned short us;
      memcpy(&us, &hb, 2);
      B[j] = (short)us;
    }

    float4_ D0 = {0.f, 0.f, 0.f, 0.f};
    float4_ D1 = {0.f, 0.f, 0.f, 0.f};
    D0 = __builtin_amdgcn_mfma_f32_16x16x32_bf16(A0, B, D0, 0, 0, 0);
    D1 = __builtin_amdgcn_mfma_f32_16x16x32_bf16(A1, B, D1, 0, 0, 0);

    // stage result (+residual) into this wave's private LDS slab
#pragma unroll
    for (int r = 0; r < 4; ++r) {
      so[(q * 4 + r) * OST + t * 16 + colL] = D0[r] + xr0[r];
      so[(16 + q * 4 + r) * OST + t * 16 + colL] = D1[r] + xr1[r];
    }
  }

  // ---- dense store: 32 ch x 128 B full-line runs (wave-private, no barrier;
  // compiler inserts lgkmcnt wait on the LDS RAW dependency) ----
#pragma unroll
  for (int i = 0; i < 4; ++i) {
    const int idx = i * 64 + lane;  // 0..255
    const int ch = idx >> 3;        // 0..31
    const int slot = idx & 7;       // 8 x float4 = 32 px
    const float* sp = &so[ch * OST + slot * 4];
    float2 v0 = reinterpret_cast<const float2*>(sp)[0];
    float2 v1 = reinterpret_cast<const float2*>(sp)[1];
    float4 v = make_float4(v0.x, v0.y, v1.x, v1.y);
    *reinterpret_cast<float4*>(ob + (size_t)ch * HW + pw + slot * 4) = v;
  }
}

extern "C" void kernel_launch(void* const* d_in, const int* in_sizes, int n_in,
                              void* d_out, int out_size, void* d_ws, size_t ws_size,
                              hipStream_t stream) {
  const float* x     = (const float*)d_in[0];
  const float* prev  = (const float*)d_in[1];
  const float* g1    = (const float*)d_in[2];
  const float* be1   = (const float*)d_in[3];
  const float* m1    = (const float*)d_in[4];
  const float* v1    = (const float*)d_in[5];
  const float* g2    = (const float*)d_in[6];
  const float* be2   = (const float*)d_in[7];
  const float* m2    = (const float*)d_in[8];
  const float* v2    = (const float*)d_in[9];
  const float* w1    = (const float*)d_in[10];
  const float* w2    = (const float*)d_in[11];
  const float* shift = (const float*)d_in[12];

  float* out  = (float*)d_out;
  float* fmap = out + (size_t)NB * CC * HW;  // second output, written in place
  float* ws   = (float*)d_ws;

  precompute_k<<<12, 128, 0, stream>>>(g1, be1, m1, v1, g2, be2, m2, v2,
                                       w1, w2, shift, ws);
  k1_conv1<<<dim3(1568, 2), 256, 0, stream>>>(x, prev, ws, fmap);
  k2_shift_conv2<<<dim3(784, 3), 256, 0, stream>>>(x, fmap, ws, out);
}

// Round 18
// 53.371 us; speedup vs baseline: 1.1244x; 1.0117x over previous
//
#include <hip/hip_runtime.h>
#include <hip/hip_bf16.h>
#include <string.h>

// N=32, C=96, H=W=56. HW=3136, NP=100352.
// d_out = [ out (9,633,792 f32) | fmap (9,633,792 f32) ]
//
// ws layout (float index):
//   [   0, 4608) W1 bf16 A-frags: slot ((g*3+m)*3+k)*64+lane (16 B each),
//                w'[o=16m+(lane&15)][ci=32k+(lane>>4)*8+j], w' = w1*s1
//   [4608, 4800) c1[192] f32: c = b1/s1 (act' = max(x + c, 0))
//   [4800, 6336) W2 bf16 A-frags: slot ((G*2+m))*64+lane,
//                w2[o=G*32+16m+(lane&15)][ci=(lane>>4)*8+j]  (no fold)
//   [6336, 7104) p2[96][8]: c2=b2/s2, w00*s2, w01*s2, w10*s2, w11*s2,
//                ayax packed, off = ay*56+ax, pad
#define WSC_OFF 4608
#define WS_W2F  4800
#define WS_P    6336

#define HW 3136
#define CC 96
#define NB 32
#define LST 66   // out-stage row stride (floats): 2-way (free) bank aliasing
#define OST 34   // K2 per-wave out-stage row stride (floats)

typedef __attribute__((ext_vector_type(8))) short short8;
typedef __attribute__((ext_vector_type(4))) float float4_;

__global__ __launch_bounds__(128) void precompute_k(
    const float* __restrict__ g1, const float* __restrict__ be1,
    const float* __restrict__ m1, const float* __restrict__ v1,
    const float* __restrict__ g2, const float* __restrict__ be2,
    const float* __restrict__ m2, const float* __restrict__ v2,
    const float* __restrict__ w1, const float* __restrict__ w2,
    const float* __restrict__ shift, float* __restrict__ ws) {
  const int t = blockIdx.x * 128 + threadIdx.x;  // 12*128 = 1536 threads
  if (t < 192) {
    float s = g1[t] / sqrtf(v1[t] + 1e-5f);
    float b = be1[t] - m1[t] * s;
    ws[WSC_OFF + t] = b / s;     // gamma > 0 guaranteed
  }
  if (t >= 192 && t < 288) {     // conv2 per-channel params (s2 folded into w)
    int c = t - 192;
    float s = g2[c] / sqrtf(v2[c] + 1e-5f);
    float b = be2[c] - m2[c] * s;
    float dy = shift[2 * c], dx = shift[2 * c + 1];
    float fy = floorf(dy), fx = floorf(dx);
    float wy = dy - fy, wx = dx - fx;
    int ay = (int)fy, ax = (int)fx;
    float* pp = ws + WS_P + c * 8;
    pp[0] = b / s;                       // c2: q = s*relu(f + c2)
    pp[1] = (1.f - wy) * (1.f - wx) * s;
    pp[2] = (1.f - wy) * wx * s;
    pp[3] = wy * (1.f - wx) * s;
    pp[4] = wy * wx * s;
    pp[5] = __int_as_float((ay << 16) | (ax & 0xffff));
    pp[6] = __int_as_float(ay * 56 + ax);
    pp[7] = 0.f;
  }
  if (t < 1152) {                // W1 fragments (scale-folded bf16)
    const int lane = t & 63;
    const int gmk = t >> 6;      // 0..17
    const int k = gmk % 3;
    const int gm = gmk / 3;
    const int m = gm % 3;
    const int g = gm / 3;
    const int o = 16 * m + (lane & 15);
    const int ci0 = 32 * k + (lane >> 4) * 8;
    unsigned int pk[4];
    for (int jj = 0; jj < 4; ++jj) {
      unsigned short us[2];
      for (int h = 0; h < 2; ++h) {
        int ci = ci0 + 2 * jj + h;
        float s = g1[g * 96 + ci] / sqrtf(v1[g * 96 + ci] + 1e-5f);
        float w = w1[(g * 48 + o) * 96 + ci] * s;
        __hip_bfloat16 hb = __float2bfloat16(w);
        memcpy(&us[h], &hb, 2);
      }
      pk[jj] = (unsigned int)us[0] | ((unsigned int)us[1] << 16);
    }
    uint4 val;
    val.x = pk[0]; val.y = pk[1]; val.z = pk[2]; val.w = pk[3];
    ((uint4*)ws)[t] = val;
  } else if (t < 1536) {         // W2 fragments (plain bf16)
    const int s2i = t - 1152;    // 0..383
    const int lane = s2i & 63;
    const int gm = s2i >> 6;     // 0..5
    const int m = gm & 1;
    const int G = gm >> 1;
    const int o = G * 32 + m * 16 + (lane & 15);
    const int k0 = (lane >> 4) * 8;
    unsigned int pk[4];
    for (int jj = 0; jj < 4; ++jj) {
      unsigned short us[2];
      for (int h = 0; h < 2; ++h) {
        __hip_bfloat16 hb = __float2bfloat16(w2[o * 32 + k0 + 2 * jj + h]);
        memcpy(&us[h], &hb, 2);
      }
      pk[jj] = (unsigned int)us[0] | ((unsigned int)us[1] << 16);
    }
    uint4 val;
    val.x = pk[0]; val.y = pk[1]; val.z = pk[2]; val.w = pk[3];
    ((uint4*)(ws + WS_W2F))[s2i] = val;
  }
}

// ---------------------------------------------------------------------------
// K1 (MFMA): fmap = conv1x1_g2( bnrelu1( concat ), w1 )
// grid (1568, 2): 64-px strip x group; block 256 = 4 waves, wave = one
// 16-px tile. Direct strided reads (r16 proved staging-in is a null);
// out-stage ONLY: D -> sOut[48][66] -> one barrier -> dense 256 B/channel
// float4 stores (r17 proved full-line stores kill write-allocate fetches).
// LDS 12.7 KB -> 8 blocks/CU (32 waves/CU, threads-limited); 1 barrier.
// ---------------------------------------------------------------------------
__global__ __launch_bounds__(256) void k1_conv1(
    const float* __restrict__ x, const float* __restrict__ prev,
    const float* __restrict__ ws, float* __restrict__ fmap) {
  __shared__ float sOut[48 * LST];   // 12,672 B

  const int tid = threadIdx.x;
  const int lane = tid & 63;
  const int wv = tid >> 6;       // 0..3
  const int g = blockIdx.y;
  const int strip = blockIdx.x;  // linear, 64-px strips
  const int q = lane >> 4;       // 0..3
  const int colL = lane & 15;

  short8 A[3][3];
  const short8* wf = (const short8*)ws;
#pragma unroll
  for (int m = 0; m < 3; ++m)
#pragma unroll
    for (int k = 0; k < 3; ++k)
      A[m][k] = wf[((g * 3 + m) * 3 + k) * 64 + lane];

  float c_[3][8];
#pragma unroll
  for (int k = 0; k < 3; ++k) {
    const float* cp = ws + WSC_OFF + g * 96 + 32 * k + 8 * q;
#pragma unroll
    for (int j = 0; j < 8; ++j) c_[k][j] = cp[j];
  }

  const int P0 = strip * 64;     // 64 | 3136: whole block in one image
  const int n = P0 / HW;
  const int p0 = P0 - n * HW;
  const size_t nb = (size_t)n * CC * HW;
  const int px = wv * 16 + colL; // block-local px 0..63
  const int col = p0 + px;

  // per-k source base (octets never straddle the x/prev split)
  const float* sb[3];
#pragma unroll
  for (int k = 0; k < 3; ++k) {
    const int ci0 = 32 * k + 8 * q;
    sb[k] = (ci0 < 48)
        ? (x + nb + (size_t)(g * 48 + ci0) * HW)
        : (prev + nb + (size_t)((1 - g) * 48 + (ci0 - 48)) * HW);
  }

  float4_ D[3] = {{0.f, 0.f, 0.f, 0.f}, {0.f, 0.f, 0.f, 0.f},
                  {0.f, 0.f, 0.f, 0.f}};
#pragma unroll
  for (int k = 0; k < 3; ++k) {
    float a[8];
#pragma unroll
    for (int j = 0; j < 8; ++j) a[j] = sb[k][(size_t)j * HW + col];
    short8 B;
#pragma unroll
    for (int j = 0; j < 8; ++j) {
      float f = fmaxf(a[j] + c_[k][j], 0.f);
      __hip_bfloat16 hb = __float2bfloat16(f);
      unsigned short us;
      memcpy(&us, &hb, 2);
      B[j] = (short)us;
    }
#pragma unroll
    for (int m = 0; m < 3; ++m)
      D[m] = __builtin_amdgcn_mfma_f32_16x16x32_bf16(A[m][k], B, D[m],
                                                     0, 0, 0);
  }

  // stage out (2-way-free banks), one barrier, dense full-line stores
#pragma unroll
  for (int m = 0; m < 3; ++m)
#pragma unroll
    for (int r = 0; r < 4; ++r)
      sOut[(16 * m + 4 * q + r) * LST + px] = D[m][r];
  __syncthreads();

  float* fb = fmap + nb + (size_t)(g * 48) * HW;
#pragma unroll
  for (int i = 0; i < 3; ++i) {
    const int idx = i * 256 + tid;  // 0..767
    const int row = idx >> 4;       // 0..47
    const int px4 = idx & 15;
    const float* sp = &sOut[row * LST + px4 * 4];
    float2 v0 = reinterpret_cast<const float2*>(sp)[0];
    float2 v1 = reinterpret_cast<const float2*>(sp)[1];
    float4 v = make_float4(v0.x, v0.y, v1.x, v1.y);
    *reinterpret_cast<float4*>(fb + (size_t)row * HW + p0 + px4 * 4) = v;
  }
}

// ---------------------------------------------------------------------------
// K2 (MFMA): out = conv1x1_g3( active_shift( bnrelu2(fmap) ), w2 ) + x
// grid (784, 3) LINEAR, 128-px strips; block 256 = 4 waves; wave = 2 tiles.
// s2 folded into tap weights; per-wave LDS out-staging -> dense 128 B runs.
// (r17's exact kernel, ~13 us.)
// ---------------------------------------------------------------------------
__global__ __launch_bounds__(256) void k2_shift_conv2(
    const float* __restrict__ x, const float* __restrict__ fmap,
    const float* __restrict__ ws, float* __restrict__ out) {
  __shared__ float sO[4][32 * OST];   // 4 waves x 4352 B = 17,408 B

  const int tid = threadIdx.x;
  const int G = blockIdx.y;        // group 0..2
  const int lane = tid & 63;
  const int wv = tid >> 6;         // 0..3
  const int q = lane >> 4;
  const int colL = lane & 15;
  const int strip = blockIdx.x;    // linear, same px order as K1

  short8 A0, A1;
  {
    const short8* wf2 = (const short8*)(ws + WS_W2F);
    A0 = wf2[(G * 2 + 0) * 64 + lane];
    A1 = wf2[(G * 2 + 1) * 64 + lane];
  }

  float c2_[8], w00_[8], w01_[8], w10_[8], w11_[8];
  int off_[8], ay_[8], ax_[8];
#pragma unroll
  for (int j = 0; j < 8; ++j) {
    const float* pp = ws + WS_P + (G * 32 + q * 8 + j) * 8;
    c2_[j] = pp[0];
    w00_[j] = pp[1];
    w01_[j] = pp[2];
    w10_[j] = pp[3];
    w11_[j] = pp[4];
    const int ayax = __float_as_int(pp[5]);
    ay_[j] = ayax >> 16;
    ax_[j] = (short)(ayax & 0xffff);
    off_[j] = __float_as_int(pp[6]);
  }

  const int Pw = strip * 128 + wv * 32;   // 32 | 3136: n const per wave
  const int n = Pw / HW;
  const int pw = Pw - n * HW;
  const int cb = n * CC + G * 32;
  const float* fb = fmap + (size_t)cb * HW;
  const float* xb = x + (size_t)cb * HW;
  float* ob = out + (size_t)cb * HW;
  float* so = &sO[wv][0];

#pragma unroll
  for (int t = 0; t < 2; ++t) {
    const int p = pw + t * 16 + colL;
    const int y = p / 56;
    const int xx = p - y * 56;

    // residual prefetch (independent of gather chain)
    float xr0[4], xr1[4];
#pragma unroll
    for (int r = 0; r < 4; ++r) {
      xr0[r] = xb[(size_t)(q * 4 + r) * HW + p];
      xr1[r] = xb[(size_t)(16 + q * 4 + r) * HW + p];
    }

    short8 B;
#pragma unroll
    for (int j = 0; j < 8; ++j) {
      const int ci = q * 8 + j;
      const float* fc = fb + (size_t)ci * HW;
      const int to = p + off_[j];
      float f00 = fc[to];
      float f01 = fc[min(to + 1, HW - 1)];
      float f10 = fc[min(to + 56, HW - 1)];
      float f11 = fc[min(to + 57, HW - 1)];
      float q00 = fmaxf(f00 + c2_[j], 0.f);
      float q01 = fmaxf(f01 + c2_[j], 0.f);
      float q10 = fmaxf(f10 + c2_[j], 0.f);
      float q11 = fmaxf(f11 + c2_[j], 0.f);
      const int yq = y + ay_[j], xq = xx + ax_[j];
      const bool vy0 = yq >= 0, vy1 = yq <= 54;
      const bool vx0 = xq >= 0, vx1 = xq <= 54;
      float h = ((vy0 && vx0) ? w00_[j] : 0.f) * q00;
      h = fmaf(((vy0 && vx1) ? w01_[j] : 0.f), q01, h);
      h = fmaf(((vy1 && vx0) ? w10_[j] : 0.f), q10, h);
      h = fmaf(((vy1 && vx1) ? w11_[j] : 0.f), q11, h);
      __hip_bfloat16 hb = __float2bfloat16(h);
      unsigned short us;
      memcpy(&us, &hb, 2);
      B[j] = (short)us;
    }

    float4_ D0 = {0.f, 0.f, 0.f, 0.f};
    float4_ D1 = {0.f, 0.f, 0.f, 0.f};
    D0 = __builtin_amdgcn_mfma_f32_16x16x32_bf16(A0, B, D0, 0, 0, 0);
    D1 = __builtin_amdgcn_mfma_f32_16x16x32_bf16(A1, B, D1, 0, 0, 0);

    // stage result (+residual) into this wave's private LDS slab
#pragma unroll
    for (int r = 0; r < 4; ++r) {
      so[(q * 4 + r) * OST + t * 16 + colL] = D0[r] + xr0[r];
      so[(16 + q * 4 + r) * OST + t * 16 + colL] = D1[r] + xr1[r];
    }
  }

  // dense store: 32 ch x 128 B full-line runs (wave-private, no barrier)
#pragma unroll
  for (int i = 0; i < 4; ++i) {
    const int idx = i * 64 + lane;  // 0..255
    const int ch = idx >> 3;        // 0..31
    const int slot = idx & 7;       // 8 x float4 = 32 px
    const float* sp = &so[ch * OST + slot * 4];
    float2 v0 = reinterpret_cast<const float2*>(sp)[0];
    float2 v1 = reinterpret_cast<const float2*>(sp)[1];
    float4 v = make_float4(v0.x, v0.y, v1.x, v1.y);
    *reinterpret_cast<float4*>(ob + (size_t)ch * HW + pw + slot * 4) = v;
  }
}

extern "C" void kernel_launch(void* const* d_in, const int* in_sizes, int n_in,
                              void* d_out, int out_size, void* d_ws, size_t ws_size,
                              hipStream_t stream) {
  const float* x     = (const float*)d_in[0];
  const float* prev  = (const float*)d_in[1];
  const float* g1    = (const float*)d_in[2];
  const float* be1   = (const float*)d_in[3];
  const float* m1    = (const float*)d_in[4];
  const float* v1    = (const float*)d_in[5];
  const float* g2    = (const float*)d_in[6];
  const float* be2   = (const float*)d_in[7];
  const float* m2    = (const float*)d_in[8];
  const float* v2    = (const float*)d_in[9];
  const float* w1    = (const float*)d_in[10];
  const float* w2    = (const float*)d_in[11];
  const float* shift = (const float*)d_in[12];

  float* out  = (float*)d_out;
  float* fmap = out + (size_t)NB * CC * HW;  // second output, written in place
  float* ws   = (float*)d_ws;

  precompute_k<<<12, 128, 0, stream>>>(g1, be1, m1, v1, g2, be2, m2, v2,
                                       w1, w2, shift, ws);
  k1_conv1<<<dim3(1568, 2), 256, 0, stream>>>(x, prev, ws, fmap);
  k2_shift_conv2<<<dim3(784, 3), 256, 0, stream>>>(x, fmap, ws, out);
}